// Round 1
// baseline (341.721 us; speedup 1.0000x reference)
//
#include <hip/hip_runtime.h>
#include <hip/hip_bf16.h>

// MoE MLP, top-1 routing + shared expert.  T=2048 H=768 I=2048 E=8, f32 in/out.
// Strategy: route tokens (f64-accurate argmax), then grouped bf16-MFMA GEMMs:
//   stage A: P[tok,i] = silu(x*s @ Wg) * (x*s @ Wu)   (bf16 in ws)
//   stage B: out[tok,h] = P @ Wd  (+ shared expert path, f32 accumulate)

#define TT 2048
#define HH 768
#define II 2048
#define NE 8
#define LDA 40   // LDS row stride in u16: 32 data + 8 pad (80B rows -> conflict-free-ish)

typedef unsigned short u16;
typedef unsigned int u32;
typedef short s16x8 __attribute__((ext_vector_type(8)));   // 8 bf16 for MFMA operand
typedef u16 u16x8 __attribute__((ext_vector_type(8)));
typedef u16 u16x4 __attribute__((ext_vector_type(4)));
typedef float f32x4 __attribute__((ext_vector_type(4)));

__device__ __forceinline__ u16 f2bf(float f) {  // f32 -> bf16 RNE (no NaN inputs here)
  u32 u = __builtin_bit_cast(u32, f);
  return (u16)((u + 0x7FFFu + ((u >> 16) & 1u)) >> 16);
}

// ---------------- router + dispatch ----------------
__global__ void router_kernel(const float* __restrict__ x, const float* __restrict__ rw,
                              float* __restrict__ score, int* __restrict__ list,
                              int* __restrict__ cnt, float* __restrict__ probsum) {
  const int t = (int)((blockIdx.x * blockDim.x + threadIdx.x) >> 6);  // one wave per token
  const int lane = threadIdx.x & 63;
  if (t >= TT) return;
  double acc[NE];
#pragma unroll
  for (int e = 0; e < NE; ++e) acc[e] = 0.0;
  const float* xr = x + (size_t)t * HH;
  for (int h = lane; h < HH; h += 64) {
    const double xv = (double)xr[h];
#pragma unroll
    for (int e = 0; e < NE; ++e) acc[e] += xv * (double)rw[h * NE + e];
  }
#pragma unroll
  for (int off = 32; off > 0; off >>= 1) {
#pragma unroll
    for (int e = 0; e < NE; ++e) acc[e] += __shfl_xor(acc[e], off);
  }
  if (lane == 0) {
    int best = 0;
#pragma unroll
    for (int e = 1; e < NE; ++e)
      if (acc[e] > acc[best]) best = e;   // strict > == first-max, matches jnp.argmax
    const float sc = 1.0f / (1.0f + __expf((float)(-acc[best])));
    score[t] = sc;
    const int pos = atomicAdd(&cnt[best], 1);
    list[best * TT + pos] = t;
    atomicAdd(&probsum[best], sc);
  }
}

__global__ void loss_kernel(const int* __restrict__ cnt, const float* __restrict__ probsum,
                            float* __restrict__ out) {
  if (threadIdx.x == 0) {
    float s = 0.0f;
#pragma unroll
    for (int e = 0; e < NE; ++e) s += (float)cnt[e] * probsum[e];
    out[(size_t)TT * HH] = s * (0.001f * (float)NE / ((float)TT * (float)TT));
  }
}

// ---------------- stage A: P = silu(X Wg) * (X Wu) ----------------
// grid: (nt=16, mt=16, g=9)  g<8 experts (gathered+scaled rows), g==8 shared (raw x)
__global__ __launch_bounds__(256, 2) void stageA_kernel(
    const float* __restrict__ x, const float* __restrict__ score,
    const int* __restrict__ list, const int* __restrict__ cnt,
    const float* __restrict__ gate_w, const float* __restrict__ up_w,
    const float* __restrict__ sh_gate, const float* __restrict__ sh_up,
    u16* __restrict__ P) {
  const int g = blockIdx.z;
  const int mt = blockIdx.y;
  const int nt = blockIdx.x;
  const bool routed = (g < NE);
  const int n_rows = routed ? cnt[g] : TT;
  if (mt * 128 >= n_rows) return;

  const float* Wg = routed ? gate_w + (size_t)g * HH * II : sh_gate;
  const float* Wu = routed ? up_w + (size_t)g * HH * II : sh_up;
  u16* Pout = P + (routed ? (size_t)0 : (size_t)TT * II);

  __shared__ u16 As[128 * LDA];
  __shared__ u16 Bg[128 * LDA];
  __shared__ u16 Bu[128 * LDA];

  const int tid = threadIdx.x;
  // A staging: thread -> (row, 16-wide k group)
  const int ar = tid >> 1;
  const int akg = (tid & 1) * 16;
  const int arow = mt * 128 + ar;
  int atok;
  float ascale;
  if (routed) {
    const bool v = (arow < n_rows);
    atok = v ? list[g * TT + arow] : 0;
    ascale = v ? score[atok] : 0.0f;
  } else {
    atok = arow;
    ascale = 1.0f;
  }
  const float* xrow = x + (size_t)atok * HH + akg;

  // B staging: thread -> 4 n-cols x 4 k-rows (transpose into [n][k])
  const int bn0 = (tid >> 3) * 4;
  const int bkq = (tid & 7) * 4;
  const int ncol = nt * 128;

  const int lane = tid & 63;
  const int wid = tid >> 6;
  const int wm = (wid >> 1) * 64;
  const int wn = (wid & 1) * 64;
  const int fr = lane & 15;
  const int fq = lane >> 4;

  f32x4 accg[4][4], accu[4][4];
#pragma unroll
  for (int i = 0; i < 4; ++i)
#pragma unroll
    for (int j = 0; j < 4; ++j) {
      accg[i][j] = f32x4{0.f, 0.f, 0.f, 0.f};
      accu[i][j] = f32x4{0.f, 0.f, 0.f, 0.f};
    }

  for (int k0 = 0; k0 < HH; k0 += 32) {
    {  // x tile (scaled, f32 -> bf16)
      const f32x4* xp = reinterpret_cast<const f32x4*>(xrow + k0);
      const f32x4 q0 = xp[0], q1 = xp[1], q2 = xp[2], q3 = xp[3];
      u16x8 w0, w1;
#pragma unroll
      for (int j = 0; j < 4; ++j) {
        w0[j] = f2bf(q0[j] * ascale);
        w0[j + 4] = f2bf(q1[j] * ascale);
        w1[j] = f2bf(q2[j] * ascale);
        w1[j + 4] = f2bf(q3[j] * ascale);
      }
      *reinterpret_cast<u16x8*>(&As[ar * LDA + akg]) = w0;
      *reinterpret_cast<u16x8*>(&As[ar * LDA + akg + 8]) = w1;
    }
#pragma unroll
    for (int m = 0; m < 2; ++m) {  // gate then up weight tile, transposed to [n][k]
      const float* W = m ? Wu : Wg;
      u16* Bs = m ? Bu : Bg;
      f32x4 q[4];
#pragma unroll
      for (int i = 0; i < 4; ++i)
        q[i] = *reinterpret_cast<const f32x4*>(&W[(size_t)(k0 + bkq + i) * II + ncol + bn0]);
#pragma unroll
      for (int n = 0; n < 4; ++n) {
        u16x4 pk;
#pragma unroll
        for (int i = 0; i < 4; ++i) pk[i] = f2bf(q[i][n]);
        *reinterpret_cast<u16x4*>(&Bs[(bn0 + n) * LDA + bkq]) = pk;
      }
    }
    __syncthreads();

    s16x8 af[4];
#pragma unroll
    for (int i = 0; i < 4; ++i)
      af[i] = *reinterpret_cast<const s16x8*>(&As[(wm + i * 16 + fr) * LDA + fq * 8]);
#pragma unroll
    for (int j = 0; j < 4; ++j) {
      const s16x8 bg = *reinterpret_cast<const s16x8*>(&Bg[(wn + j * 16 + fr) * LDA + fq * 8]);
      const s16x8 bu = *reinterpret_cast<const s16x8*>(&Bu[(wn + j * 16 + fr) * LDA + fq * 8]);
#pragma unroll
      for (int i = 0; i < 4; ++i) {
        accg[i][j] = __builtin_amdgcn_mfma_f32_16x16x32_bf16(af[i], bg, accg[i][j], 0, 0, 0);
        accu[i][j] = __builtin_amdgcn_mfma_f32_16x16x32_bf16(af[i], bu, accu[i][j], 0, 0, 0);
      }
    }
    __syncthreads();
  }

  // epilogue: silu(g)*u -> bf16 P[token][i]
#pragma unroll
  for (int i = 0; i < 4; ++i) {
#pragma unroll
    for (int c = 0; c < 4; ++c) {
      const int r = wm + i * 16 + fq * 4 + c;  // C/D: row=(lane>>4)*4+reg, col=lane&15
      const int row = mt * 128 + r;
      const bool v = (row < n_rows);
      if (v) {
        const int tok = routed ? list[g * TT + row] : row;
#pragma unroll
        for (int j = 0; j < 4; ++j) {
          const float gv = accg[i][j][c];
          const float uv = accu[i][j][c];
          const float val = (gv / (1.0f + __expf(-gv))) * uv;
          Pout[(size_t)tok * II + ncol + wn + j * 16 + fr] = f2bf(val);
        }
      }
    }
  }
}

// ---------------- stage B: out = P Wd (+=) ----------------
// shared variant (ROUTED=false): plain stores, covers every out element.
// routed variant: each (token,h) owned by exactly one block -> plain RMW add.
template <bool ROUTED>
__global__ __launch_bounds__(256, 2) void stageB_kernel(
    const u16* __restrict__ P, const int* __restrict__ list, const int* __restrict__ cnt,
    const float* __restrict__ down_w, const float* __restrict__ sh_down,
    float* __restrict__ out) {
  const int g = blockIdx.z;
  const int mt = blockIdx.y;
  const int nt = blockIdx.x;
  const int n_rows = ROUTED ? cnt[g] : TT;
  if (mt * 128 >= n_rows) return;
  const u16* Pin = ROUTED ? P : P + (size_t)TT * II;
  const float* W = ROUTED ? down_w + (size_t)g * II * HH : sh_down;

  __shared__ u16 As[128 * LDA];
  __shared__ u16 Bs[128 * LDA];

  const int tid = threadIdx.x;
  const int ar = tid >> 1;
  const int akg = (tid & 1) * 16;
  const int arow = mt * 128 + ar;
  int atok;
  if (ROUTED)
    atok = (arow < n_rows) ? list[g * TT + arow] : 0;
  else
    atok = arow;
  const u16* prow = Pin + (size_t)atok * II + akg;

  const int bn0 = (tid >> 3) * 4;
  const int bkq = (tid & 7) * 4;
  const int ncol = nt * 128;

  const int lane = tid & 63;
  const int wid = tid >> 6;
  const int wm = (wid >> 1) * 64;
  const int wn = (wid & 1) * 64;
  const int fr = lane & 15;
  const int fq = lane >> 4;

  f32x4 acc[4][4];
#pragma unroll
  for (int i = 0; i < 4; ++i)
#pragma unroll
    for (int j = 0; j < 4; ++j) acc[i][j] = f32x4{0.f, 0.f, 0.f, 0.f};

  for (int k0 = 0; k0 < II; k0 += 32) {
    *reinterpret_cast<u16x8*>(&As[ar * LDA + akg]) =
        *reinterpret_cast<const u16x8*>(&prow[k0]);
    *reinterpret_cast<u16x8*>(&As[ar * LDA + akg + 8]) =
        *reinterpret_cast<const u16x8*>(&prow[k0 + 8]);
    f32x4 q[4];
#pragma unroll
    for (int i = 0; i < 4; ++i)
      q[i] = *reinterpret_cast<const f32x4*>(&W[(size_t)(k0 + bkq + i) * HH + ncol + bn0]);
#pragma unroll
    for (int n = 0; n < 4; ++n) {
      u16x4 pk;
#pragma unroll
      for (int i = 0; i < 4; ++i) pk[i] = f2bf(q[i][n]);
      *reinterpret_cast<u16x4*>(&Bs[(bn0 + n) * LDA + bkq]) = pk;
    }
    __syncthreads();

    s16x8 af[4];
#pragma unroll
    for (int i = 0; i < 4; ++i)
      af[i] = *reinterpret_cast<const s16x8*>(&As[(wm + i * 16 + fr) * LDA + fq * 8]);
#pragma unroll
    for (int j = 0; j < 4; ++j) {
      const s16x8 bf = *reinterpret_cast<const s16x8*>(&Bs[(wn + j * 16 + fr) * LDA + fq * 8]);
#pragma unroll
      for (int i = 0; i < 4; ++i)
        acc[i][j] = __builtin_amdgcn_mfma_f32_16x16x32_bf16(af[i], bf, acc[i][j], 0, 0, 0);
    }
    __syncthreads();
  }

#pragma unroll
  for (int i = 0; i < 4; ++i) {
#pragma unroll
    for (int c = 0; c < 4; ++c) {
      const int r = wm + i * 16 + fq * 4 + c;
      const int row = mt * 128 + r;
      const bool v = (row < n_rows);
      if (v) {
        const int tok = ROUTED ? list[g * TT + row] : row;
#pragma unroll
        for (int j = 0; j < 4; ++j) {
          const int col = ncol + wn + j * 16 + fr;
          const float val = acc[i][j][c];
          if (ROUTED)
            out[(size_t)tok * HH + col] += val;  // unique owner, shared pass already done
          else
            out[(size_t)tok * HH + col] = val;
        }
      }
    }
  }
}

// ---------------- launcher ----------------
extern "C" void kernel_launch(void* const* d_in, const int* in_sizes, int n_in,
                              void* d_out, int out_size, void* d_ws, size_t ws_size,
                              hipStream_t stream) {
  (void)in_sizes; (void)n_in; (void)out_size; (void)ws_size;
  const float* x = (const float*)d_in[0];
  const float* rw = (const float*)d_in[1];
  const float* gate_w = (const float*)d_in[2];
  const float* up_w = (const float*)d_in[3];
  const float* down_w = (const float*)d_in[4];
  const float* sh_gate = (const float*)d_in[5];
  const float* sh_up = (const float*)d_in[6];
  const float* sh_down = (const float*)d_in[7];
  float* out = (float*)d_out;

  char* ws = (char*)d_ws;
  u16* P = (u16*)ws;                                   // [2][T][I] bf16: routed, shared
  size_t off = (size_t)2 * TT * II * sizeof(u16);      // 16 MiB
  float* score = (float*)(ws + off); off += TT * sizeof(float);
  int* list = (int*)(ws + off);      off += (size_t)NE * TT * sizeof(int);
  int* cnt = (int*)(ws + off);       off += 16 * sizeof(int);
  float* probsum = (float*)(ws + off);

  hipMemsetAsync(cnt, 0, 16 * sizeof(int) + 16 * sizeof(float), stream);
  router_kernel<<<dim3(512), dim3(256), 0, stream>>>(x, rw, score, list, cnt, probsum);
  loss_kernel<<<dim3(1), dim3(64), 0, stream>>>(cnt, probsum, out);
  stageA_kernel<<<dim3(16, 16, 9), dim3(256), 0, stream>>>(x, score, list, cnt, gate_w,
                                                           up_w, sh_gate, sh_up, P);
  stageB_kernel<false><<<dim3(6, 16, 1), dim3(256), 0, stream>>>(P, list, cnt, down_w,
                                                                 sh_down, out);
  stageB_kernel<true><<<dim3(6, 16, 8), dim3(256), 0, stream>>>(P, list, cnt, down_w,
                                                                sh_down, out);
}

// Round 2
// 285.610 us; speedup vs baseline: 1.1965x; 1.1965x over previous
//
#include <hip/hip_runtime.h>
#include <hip/hip_bf16.h>

// MoE MLP top-1 + shared expert. T=2048 H=768 I=2048 E=8, f32 in/out.
// Pipeline: router -> plan (padded segments) -> gather (bf16 tiled Xc) ->
//   stageA (P = silu(Xc Wg) * (Xc Wu), gll A-operand, reg-converted W) ->
//   stageB (out += P Wd, atomicAdd epilogue).
// Activation tiling (Xc, P): row-tile rt=p>>7, chunk c=k>>5, then
//   u16 addr = (rt*NC + c)*4096 + ((p>>4)&7)*512 + ((k>>3)&3)*128 + (p&15)*8 + (k&7)
// => global_load_lds copies a chunk linearly; MFMA A-fragment reads are
//    linear-in-lane (conflict-free).

#define TT 2048
#define HH 768
#define II 2048
#define NE 8
#define RSLOTS 3072   // routed padded slots (24 tiles of 128); 2048+7*128 <= 3072
#define LDB 34        // LDS B row stride (u16): 17 banks, odd -> conflict-free

typedef unsigned short u16;
typedef unsigned int u32;
typedef short s16x8 __attribute__((ext_vector_type(8)));
typedef u16 u16x8 __attribute__((ext_vector_type(8)));
typedef u16 u16x4 __attribute__((ext_vector_type(4)));
typedef float f32x4 __attribute__((ext_vector_type(4)));

__device__ __forceinline__ u16 f2bf(float f) {  // f32 -> bf16 RNE
  u32 u = __builtin_bit_cast(u32, f);
  return (u16)((u + 0x7FFFu + ((u >> 16) & 1u)) >> 16);
}

typedef __attribute__((address_space(3))) u32 lds_u32;
typedef const __attribute__((address_space(1))) u32 glb_u32;
__device__ __forceinline__ void gll16(const void* g, void* l) {
  // LDS dest: wave-uniform base + lane*16 (linear). 16B per lane.
  __builtin_amdgcn_global_load_lds((glb_u32*)g,
                                   (lds_u32*)(u32)(unsigned long long)l, 16, 0, 0);
}

// ---------------- router ----------------
__global__ void router_kernel(const float* __restrict__ x, const float* __restrict__ rw,
                              float* __restrict__ score, int* __restrict__ list,
                              int* __restrict__ cnt, float* __restrict__ probsum) {
  const int t = (int)((blockIdx.x * blockDim.x + threadIdx.x) >> 6);  // wave/token
  const int lane = threadIdx.x & 63;
  if (t >= TT) return;
  double acc[NE];
#pragma unroll
  for (int e = 0; e < NE; ++e) acc[e] = 0.0;
  const float* xr = x + (size_t)t * HH;
  for (int h = lane; h < HH; h += 64) {
    const double xv = (double)xr[h];
#pragma unroll
    for (int e = 0; e < NE; ++e) acc[e] += xv * (double)rw[h * NE + e];
  }
#pragma unroll
  for (int off = 32; off > 0; off >>= 1) {
#pragma unroll
    for (int e = 0; e < NE; ++e) acc[e] += __shfl_xor(acc[e], off);
  }
  if (lane == 0) {
    int best = 0;
#pragma unroll
    for (int e = 1; e < NE; ++e)
      if (acc[e] > acc[best]) best = e;  // strict > == first-max (jnp.argmax)
    const float sc = 1.0f / (1.0f + __expf((float)(-acc[best])));
    score[t] = sc;
    const int pos = atomicAdd(&cnt[best], 1);
    list[best * TT + pos] = t;
    atomicAdd(&probsum[best], sc);
  }
}

// ---------------- plan: padded segment starts + mtile->expert + loss ----------------
// meta[0..7]=seg start S[e]; meta[8]=Rp (total padded routed rows); meta[16+t]=expert of
// routed 128-row tile t (t<24).
__global__ void plan_kernel(const int* __restrict__ cnt, const float* __restrict__ probsum,
                            int* __restrict__ meta, float* __restrict__ out) {
  if (threadIdx.x == 0) {
    int S = 0;
    for (int e = 0; e < NE; ++e) {
      meta[e] = S;
      const int pad = (cnt[e] + 127) & ~127;
      for (int t = S >> 7; t < (S + pad) >> 7; ++t) meta[16 + t] = e;
      S += pad;
    }
    meta[8] = S;
    for (int t = S >> 7; t < 24; ++t) meta[16 + t] = 0;
    float s = 0.0f;
    for (int e = 0; e < NE; ++e) s += (float)cnt[e] * probsum[e];
    out[(size_t)TT * HH] = s * (0.001f * (float)NE / ((float)TT * (float)TT));
  }
}

// ---------------- gather: build tiled bf16 Xc (+tokmap) ----------------
// rows [0,RSLOTS): routed compact (x*score), zero-padded; rows [RSLOTS,5120): raw x.
__global__ __launch_bounds__(256) void gather_kernel(
    const float* __restrict__ x, const float* __restrict__ score,
    const int* __restrict__ list, const int* __restrict__ cnt,
    const int* __restrict__ meta, u16* __restrict__ Xc, int* __restrict__ tokmap) {
  const int task = blockIdx.x * 4 + (threadIdx.x >> 6);  // (16-row block, chunk)
  const int lane = threadIdx.x & 63;
  const int pb = task / 24;  // 0..319
  const int c = task % 24;   // k chunk (HH/32)
  const int fq = lane >> 4, fr = lane & 15;
  const int p = pb * 16 + fr;
  int tok;
  float sc;
  if (p >= RSLOTS) {
    tok = p - RSLOTS;
    sc = 1.0f;
  } else {
    const int e = meta[16 + (p >> 7)];
    const int idx = p - meta[e];
    tok = (idx >= 0 && idx < cnt[e]) ? list[e * TT + idx] : -1;
    sc = (tok >= 0) ? score[tok] : 0.0f;
  }
  u16x8 w = {0, 0, 0, 0, 0, 0, 0, 0};
  if (tok >= 0) {
    const float* xp = x + (size_t)tok * HH + c * 32 + fq * 8;
    const f32x4 a = *reinterpret_cast<const f32x4*>(xp);
    const f32x4 b = *reinterpret_cast<const f32x4*>(xp + 4);
#pragma unroll
    for (int j = 0; j < 4; ++j) {
      w[j] = f2bf(a[j] * sc);
      w[j + 4] = f2bf(b[j] * sc);
    }
  }
  *reinterpret_cast<u16x8*>(&Xc[((size_t)(pb >> 3) * 24 + c) * 4096 + (pb & 7) * 512 +
                                lane * 8]) = w;
  if (c == 0 && fq == 0) tokmap[p] = tok;
}

// ---------------- stage A: P = silu(Xc Wg) * (Xc Wu) ----------------
// grid (16 nt, 40 mty): mty<24 routed (early-exit past Rp), >=24 shared.
__global__ __launch_bounds__(256, 2) void stageA_kernel(
    const u16* __restrict__ Xc, const int* __restrict__ meta,
    const float* __restrict__ gate_w, const float* __restrict__ up_w,
    const float* __restrict__ sh_gate, const float* __restrict__ sh_up,
    u16* __restrict__ P) {
  const int mty = blockIdx.y;
  const int nt = blockIdx.x;
  const float *Wg, *Wu;
  if (mty < 24) {
    if (mty * 128 >= meta[8]) return;
    const int e = meta[16 + mty];
    Wg = gate_w + (size_t)e * HH * II;
    Wu = up_w + (size_t)e * HH * II;
  } else {
    Wg = sh_gate;
    Wu = sh_up;
  }
  __shared__ u16 As[2][4096];        // A chunk: 128 rows x 32 k, tiled layout
  __shared__ u16 Bgs[2][128 * LDB];  // B tiles [n][k], padded
  __shared__ u16 Bus[2][128 * LDB];

  const int tid = threadIdx.x;
  const int lane = tid & 63, wid = tid >> 6;
  const int fr = lane & 15, fq = lane >> 4;
  const int wm = (wid >> 1) * 64, wm4 = (wid >> 1) * 4;
  const int wn = (wid & 1) * 64;
  const int ncol = nt * 128;
  const int bn0 = (tid >> 3) * 4;  // B staging: 4 n-cols
  const int bkq = (tid & 7) * 4;   // 4 k-rows

  const u16* xsrc = Xc + (size_t)mty * 24 * 4096 + wid * 1024 + lane * 8;

  f32x4 accg[4][4], accu[4][4];
#pragma unroll
  for (int i = 0; i < 4; ++i)
#pragma unroll
    for (int j = 0; j < 4; ++j) {
      accg[i][j] = f32x4{0.f, 0.f, 0.f, 0.f};
      accu[i][j] = f32x4{0.f, 0.f, 0.f, 0.f};
    }

  f32x4 qg[4], qu[4];
#define STAGE_LOADS(c)                                                              \
  {                                                                                 \
    const float* pg = Wg + (size_t)((c) * 32 + bkq) * II + ncol + bn0;              \
    const float* pu = Wu + (size_t)((c) * 32 + bkq) * II + ncol + bn0;              \
    _Pragma("unroll") for (int i = 0; i < 4; ++i) {                                 \
      qg[i] = *reinterpret_cast<const f32x4*>(pg + (size_t)i * II);                 \
      qu[i] = *reinterpret_cast<const f32x4*>(pu + (size_t)i * II);                 \
    }                                                                               \
  }
#define STAGE_GLL(c, buf)                                                           \
  {                                                                                 \
    gll16(xsrc + (size_t)(c) * 4096, &As[buf][wid * 1024]);                         \
    gll16(xsrc + (size_t)(c) * 4096 + 512, &As[buf][wid * 1024 + 512]);             \
  }
#define CONV_STORE(buf)                                                             \
  {                                                                                 \
    _Pragma("unroll") for (int n = 0; n < 4; ++n) {                                 \
      u16x4 g, u;                                                                   \
      _Pragma("unroll") for (int i = 0; i < 4; ++i) {                               \
        g[i] = f2bf(qg[i][n]);                                                      \
        u[i] = f2bf(qu[i][n]);                                                      \
      }                                                                             \
      *reinterpret_cast<u16x4*>(&Bgs[buf][(bn0 + n) * LDB + bkq]) = g;              \
      *reinterpret_cast<u16x4*>(&Bus[buf][(bn0 + n) * LDB + bkq]) = u;              \
    }                                                                               \
  }

  STAGE_LOADS(0)
  STAGE_GLL(0, 0)
  CONV_STORE(0)
  __syncthreads();

  int cur = 0;
  for (int c = 0; c < 24; ++c) {
    const bool pf = (c < 23);
    if (pf) {
      STAGE_LOADS(c + 1)
      STAGE_GLL(c + 1, cur ^ 1)
    }
    s16x8 af[4];
#pragma unroll
    for (int i = 0; i < 4; ++i)
      af[i] = *reinterpret_cast<const s16x8*>(&As[cur][(wm4 + i) * 512 + fq * 128 + fr * 8]);
#pragma unroll
    for (int j = 0; j < 4; ++j) {
      const s16x8 bg =
          *reinterpret_cast<const s16x8*>(&Bgs[cur][(wn + j * 16 + fr) * LDB + fq * 8]);
      const s16x8 bu =
          *reinterpret_cast<const s16x8*>(&Bus[cur][(wn + j * 16 + fr) * LDB + fq * 8]);
#pragma unroll
      for (int i = 0; i < 4; ++i) {
        accg[i][j] = __builtin_amdgcn_mfma_f32_16x16x32_bf16(af[i], bg, accg[i][j], 0, 0, 0);
        accu[i][j] = __builtin_amdgcn_mfma_f32_16x16x32_bf16(af[i], bu, accu[i][j], 0, 0, 0);
      }
    }
    if (pf) CONV_STORE(cur ^ 1)
    __syncthreads();
    cur ^= 1;
  }

  // epilogue: silu(g)*u -> P (tiled bf16). C/D: row=fq*4+reg, col=fr (verified R1).
#pragma unroll
  for (int i = 0; i < 4; ++i)
#pragma unroll
    for (int cc = 0; cc < 4; ++cc) {
      const int rlo = fq * 4 + cc;  // p&15
#pragma unroll
      for (int j = 0; j < 4; ++j) {
        const int col = wn + j * 16 + fr;
        const int k = ncol + col;
        const float gv = accg[i][j][cc];
        const float val = (gv / (1.0f + __expf(-gv))) * accu[i][j][cc];
        P[((size_t)mty * 64 + (k >> 5)) * 4096 + (size_t)(wm4 + i) * 512 +
          ((k >> 3) & 3) * 128 + rlo * 8 + (k & 7)] = f2bf(val);
      }
    }
#undef STAGE_LOADS
#undef STAGE_GLL
#undef CONV_STORE
}

// ---------------- stage B: out += P Wd (atomicAdd) ----------------
// grid (6 nt, 80 my): my<48 routed rows p=my*64 (early-exit past Rp), >=48 shared.
__global__ __launch_bounds__(256, 2) void stageB_kernel(
    const u16* __restrict__ P, const int* __restrict__ meta,
    const int* __restrict__ tokmap, const float* __restrict__ down_w,
    const float* __restrict__ sh_down, float* __restrict__ out) {
  const int my = blockIdx.y;
  const int nt = blockIdx.x;
  const float* W;
  if (my < 48) {
    if (my * 64 >= meta[8]) return;
    W = down_w + (size_t)meta[16 + (my >> 1)] * II * HH;
  } else {
    W = sh_down;
  }
  __shared__ u16 As[2][2048];       // 64 rows x 32 k, tiled
  __shared__ u16 Bs[2][128 * LDB];  // [n=128][k=32] padded

  const int tid = threadIdx.x;
  const int lane = tid & 63, wid = tid >> 6;
  const int fr = lane & 15, fq = lane >> 4;
  const int wm = (wid >> 1) * 32;
  const int wn = (wid & 1) * 64;
  const int ncol = nt * 128;
  const int bn0 = (tid >> 3) * 4;
  const int bkq = (tid & 7) * 4;
  const int p0 = my * 64;

  const u16* psrc =
      P + (size_t)(my >> 1) * 64 * 4096 + (my & 1) * 2048 + wid * 512 + lane * 8;

  f32x4 acc[2][4];
#pragma unroll
  for (int i = 0; i < 2; ++i)
#pragma unroll
    for (int j = 0; j < 4; ++j) acc[i][j] = f32x4{0.f, 0.f, 0.f, 0.f};

  f32x4 q[4];
#define B_LOADS(c)                                                                 \
  {                                                                                \
    const float* pw = W + (size_t)((c) * 32 + bkq) * HH + ncol + bn0;              \
    _Pragma("unroll") for (int i = 0; i < 4; ++i) q[i] =                           \
        *reinterpret_cast<const f32x4*>(pw + (size_t)i * HH);                      \
  }
#define B_STORE(buf)                                                               \
  {                                                                                \
    _Pragma("unroll") for (int n = 0; n < 4; ++n) {                                \
      u16x4 pk;                                                                    \
      _Pragma("unroll") for (int i = 0; i < 4; ++i) pk[i] = f2bf(q[i][n]);         \
      *reinterpret_cast<u16x4*>(&Bs[buf][(bn0 + n) * LDB + bkq]) = pk;             \
    }                                                                              \
  }

  B_LOADS(0)
  gll16(psrc, &As[0][wid * 512]);
  B_STORE(0)
  __syncthreads();

  int cur = 0;
  for (int c = 0; c < 64; ++c) {
    const bool pf = (c < 63);
    if (pf) {
      B_LOADS(c + 1)
      gll16(psrc + (size_t)(c + 1) * 4096, &As[cur ^ 1][wid * 512]);
    }
    s16x8 af[2];
#pragma unroll
    for (int i = 0; i < 2; ++i)
      af[i] = *reinterpret_cast<const s16x8*>(
          &As[cur][((wid >> 1) * 2 + i) * 512 + fq * 128 + fr * 8]);
#pragma unroll
    for (int j = 0; j < 4; ++j) {
      const s16x8 bf =
          *reinterpret_cast<const s16x8*>(&Bs[cur][(wn + j * 16 + fr) * LDB + fq * 8]);
#pragma unroll
      for (int i = 0; i < 2; ++i)
        acc[i][j] = __builtin_amdgcn_mfma_f32_16x16x32_bf16(af[i], bf, acc[i][j], 0, 0, 0);
    }
    if (pf) B_STORE(cur ^ 1)
    __syncthreads();
    cur ^= 1;
  }

#pragma unroll
  for (int i = 0; i < 2; ++i)
#pragma unroll
    for (int cc = 0; cc < 4; ++cc) {
      const int p = p0 + wm + i * 16 + fq * 4 + cc;
      const int tok = tokmap[p];
      if (tok >= 0) {
#pragma unroll
        for (int j = 0; j < 4; ++j)
          atomicAdd(&out[(size_t)tok * HH + ncol + wn + j * 16 + fr], acc[i][j][cc]);
      }
    }
#undef B_LOADS
#undef B_STORE
}

// ---------------- launcher ----------------
extern "C" void kernel_launch(void* const* d_in, const int* in_sizes, int n_in,
                              void* d_out, int out_size, void* d_ws, size_t ws_size,
                              hipStream_t stream) {
  (void)in_sizes; (void)n_in; (void)ws_size;
  const float* x = (const float*)d_in[0];
  const float* rw = (const float*)d_in[1];
  const float* gate_w = (const float*)d_in[2];
  const float* up_w = (const float*)d_in[3];
  const float* down_w = (const float*)d_in[4];
  const float* sh_gate = (const float*)d_in[5];
  const float* sh_up = (const float*)d_in[6];
  const float* sh_down = (const float*)d_in[7];
  float* out = (float*)d_out;

  char* ws = (char*)d_ws;
  size_t off = 0;
  u16* Xc = (u16*)(ws + off); off += (size_t)(RSLOTS + TT) * HH * sizeof(u16);  // 7.9MB
  u16* P = (u16*)(ws + off);  off += (size_t)(RSLOTS + TT) * II * sizeof(u16);  // 21MB
  float* score = (float*)(ws + off); off += TT * sizeof(float);
  int* list = (int*)(ws + off);      off += (size_t)NE * TT * sizeof(int);
  int* cnt = (int*)(ws + off);       off += 16 * sizeof(int);
  float* probsum = (float*)(ws + off); off += 16 * sizeof(float);
  int* meta = (int*)(ws + off);      off += 64 * sizeof(int);
  int* tokmap = (int*)(ws + off);

  hipMemsetAsync(d_out, 0, (size_t)out_size * sizeof(float), stream);
  hipMemsetAsync(cnt, 0, 16 * sizeof(int) + 16 * sizeof(float), stream);
  router_kernel<<<dim3(512), dim3(256), 0, stream>>>(x, rw, score, list, cnt, probsum);
  plan_kernel<<<dim3(1), dim3(64), 0, stream>>>(cnt, probsum, meta, out);
  gather_kernel<<<dim3(1920), dim3(256), 0, stream>>>(x, score, list, cnt, meta, Xc,
                                                      tokmap);
  stageA_kernel<<<dim3(16, 40, 1), dim3(256), 0, stream>>>(Xc, meta, gate_w, up_w,
                                                           sh_gate, sh_up, P);
  stageB_kernel<<<dim3(6, 80, 1), dim3(256), 0, stream>>>(P, meta, tokmap, down_w,
                                                          sh_down, out);
}

// Round 4
// 206.266 us; speedup vs baseline: 1.6567x; 1.3847x over previous
//
#include <hip/hip_runtime.h>
#include <hip/hip_bf16.h>

// MoE MLP top-1 + shared expert. T=2048 H=768 I=2048 E=8, f32 in/out.
// R4 = R3 architecture with the staging bug fixed (full 8KB chunk per STAGE).
//   wconv: f32 weights -> bf16 tiled (gate/up/down + shared as expert 8)
//   gather: x -> bf16 tiled Xc (scaled routed rows compact + raw shared rows)
//   stageA: P = silu(Xc Wg) * (Xc Wu)   (gll-only staging, 32 MFMA/wave/step)
//   stageB: out += P Wd (atomicAdd epilogue via tokmap)
// Chunk = 128 rows x 32 k bf16 (4096 u16 = 8KB), in-chunk addr:
//   ((row>>4)&7)*512 + ((k>>3)&3)*128 + (row&15)*8 + (k&7)
// gll16 copies a chunk linearly; MFMA fragment reads are linear-in-lane.

#define TT 2048
#define HH 768
#define II 2048
#define NE 8
#define RSLOTS 3072   // routed padded slots (24 tiles of 128)

typedef unsigned short u16;
typedef unsigned int u32;
typedef short s16x8 __attribute__((ext_vector_type(8)));
typedef u16 u16x8 __attribute__((ext_vector_type(8)));
typedef float f32x4 __attribute__((ext_vector_type(4)));

__device__ __forceinline__ u16 f2bf(float f) {  // f32 -> bf16 RNE
  u32 u = __builtin_bit_cast(u32, f);
  return (u16)((u + 0x7FFFu + ((u >> 16) & 1u)) >> 16);
}

typedef __attribute__((address_space(3))) u32 lds_u32;
typedef const __attribute__((address_space(1))) u32 glb_u32;
__device__ __forceinline__ void gll16(const void* g, void* l) {
  // global src per-lane; LDS dest wave-uniform base + lane*16 (linear)
  __builtin_amdgcn_global_load_lds((glb_u32*)g,
                                   (lds_u32*)(u32)(unsigned long long)l, 16, 0, 0);
}

// ---------------- router ----------------
__global__ void router_kernel(const float* __restrict__ x, const float* __restrict__ rw,
                              float* __restrict__ score, int* __restrict__ list,
                              int* __restrict__ cnt, float* __restrict__ probsum) {
  const int t = (int)((blockIdx.x * blockDim.x + threadIdx.x) >> 6);  // wave/token
  const int lane = threadIdx.x & 63;
  if (t >= TT) return;
  double acc[NE];
#pragma unroll
  for (int e = 0; e < NE; ++e) acc[e] = 0.0;
  const float* xr = x + (size_t)t * HH;
  for (int h = lane; h < HH; h += 64) {
    const double xv = (double)xr[h];
#pragma unroll
    for (int e = 0; e < NE; ++e) acc[e] += xv * (double)rw[h * NE + e];
  }
#pragma unroll
  for (int off = 32; off > 0; off >>= 1) {
#pragma unroll
    for (int e = 0; e < NE; ++e) acc[e] += __shfl_xor(acc[e], off);
  }
  if (lane == 0) {
    int best = 0;
#pragma unroll
    for (int e = 1; e < NE; ++e)
      if (acc[e] > acc[best]) best = e;  // strict > == first-max (jnp.argmax)
    const float sc = 1.0f / (1.0f + __expf((float)(-acc[best])));
    score[t] = sc;
    const int pos = atomicAdd(&cnt[best], 1);
    list[best * TT + pos] = t;
    atomicAdd(&probsum[best], sc);
  }
}

// ---------------- plan: padded segments + tile->expert + loss ----------------
__global__ void plan_kernel(const int* __restrict__ cnt, const float* __restrict__ probsum,
                            int* __restrict__ meta, float* __restrict__ out) {
  if (threadIdx.x == 0) {
    int S = 0;
    for (int e = 0; e < NE; ++e) {
      meta[e] = S;
      const int pad = (cnt[e] + 127) & ~127;
      for (int t = S >> 7; t < (S + pad) >> 7; ++t) meta[16 + t] = e;
      S += pad;
    }
    meta[8] = S;
    for (int t = S >> 7; t < 24; ++t) meta[16 + t] = 0;
    float s = 0.0f;
    for (int e = 0; e < NE; ++e) s += (float)cnt[e] * probsum[e];
    out[(size_t)TT * HH] = s * (0.001f * (float)NE / ((float)TT * (float)TT));
  }
}

// ---------------- gather: x -> tiled bf16 Xc (+tokmap) ----------------
__global__ __launch_bounds__(256) void gather_kernel(
    const float* __restrict__ x, const float* __restrict__ score,
    const int* __restrict__ list, const int* __restrict__ cnt,
    const int* __restrict__ meta, u16* __restrict__ Xc, int* __restrict__ tokmap) {
  const int task = blockIdx.x * 4 + (threadIdx.x >> 6);
  const int lane = threadIdx.x & 63;
  const int pb = task / 24;  // 16-row block, 0..319
  const int c = task % 24;   // k chunk
  const int fq = lane >> 4, fr = lane & 15;
  const int p = pb * 16 + fr;
  int tok;
  float sc;
  if (p >= RSLOTS) {
    tok = p - RSLOTS;
    sc = 1.0f;
  } else {
    const int e = meta[16 + (p >> 7)];
    const int idx = p - meta[e];
    tok = (idx >= 0 && idx < cnt[e]) ? list[e * TT + idx] : -1;
    sc = (tok >= 0) ? score[tok] : 0.0f;
  }
  u16x8 w = {0, 0, 0, 0, 0, 0, 0, 0};
  if (tok >= 0) {
    const float* xp = x + (size_t)tok * HH + c * 32 + fq * 8;
    const f32x4 a = *reinterpret_cast<const f32x4*>(xp);
    const f32x4 b = *reinterpret_cast<const f32x4*>(xp + 4);
#pragma unroll
    for (int j = 0; j < 4; ++j) {
      w[j] = f2bf(a[j] * sc);
      w[j + 4] = f2bf(b[j] * sc);
    }
  }
  *reinterpret_cast<u16x8*>(&Xc[((size_t)(pb >> 3) * 24 + c) * 4096 + (pb & 7) * 512 +
                                lane * 8]) = w;
  if (c == 0 && fq == 0) tokmap[p] = tok;
}

// ---------------- wconv: f32 weights -> bf16 tiled ----------------
// chunk id space: [0,6912) gate/up (9 experts x {g,u} x 16 nt x 24 kc);
//                 [6912,10368) down (9 x 6 nt x 64 kc). expert 8 = shared.
__global__ __launch_bounds__(256) void wconv_kernel(
    const float* __restrict__ gate_w, const float* __restrict__ up_w,
    const float* __restrict__ down_w, const float* __restrict__ sh_gate,
    const float* __restrict__ sh_up, const float* __restrict__ sh_down,
    u16* __restrict__ Wgt, u16* __restrict__ Wut, u16* __restrict__ Wdt) {
  const int id = blockIdx.x * 4 + (threadIdx.x >> 6);
  const int lane = threadIdx.x & 63;
  const int fq = lane >> 4, fr = lane & 15;
  const float* src;
  u16* dst;
  int N, n0, k0;
  if (id < 6912) {
    const int m = id / 384;  // 0..17: expert e=m>>1, mat=m&1
    const int r = id % 384;
    const int e = m >> 1;
    const int nt = r / 24, kc = r % 24;
    src = (m & 1) ? (e < 8 ? up_w + (size_t)e * HH * II : sh_up)
                  : (e < 8 ? gate_w + (size_t)e * HH * II : sh_gate);
    N = II;
    n0 = nt * 128;
    k0 = kc * 32;
    dst = ((m & 1) ? Wut : Wgt) + ((size_t)(e * 16 + nt) * 24 + kc) * 4096;
  } else {
    const int id2 = id - 6912;
    const int e = id2 / 384;
    const int r = id2 % 384;
    const int nt = r / 64, kc = r % 64;
    src = (e < 8) ? down_w + (size_t)e * II * HH : sh_down;
    N = HH;
    n0 = nt * 128;
    k0 = kc * 32;
    dst = Wdt + ((size_t)(e * 6 + nt) * 64 + kc) * 4096;
  }
  // lane (fq,fr): k-quarter fq (8 k's), col fr within 16-col group nq
  const float* colp = src + (size_t)(k0 + fq * 8) * N + n0 + fr;
#pragma unroll
  for (int nq = 0; nq < 8; ++nq) {
    const float* cp = colp + nq * 16;
    u16x8 w;
#pragma unroll
    for (int kk = 0; kk < 8; ++kk) w[kk] = f2bf(cp[(size_t)kk * N]);
    *reinterpret_cast<u16x8*>(&dst[nq * 512 + fq * 128 + fr * 8]) = w;
  }
}

// ---------------- stage A: P = silu(Xc Wg) * (Xc Wu) ----------------
// grid (16 nt, 40 mty): mty<24 routed (early-exit past Rp), >=24 shared (e=8).
__global__ __launch_bounds__(256, 2) void stageA_kernel(
    const u16* __restrict__ Xc, const int* __restrict__ meta,
    const u16* __restrict__ Wgt, const u16* __restrict__ Wut, u16* __restrict__ P) {
  const int mty = blockIdx.y, nt = blockIdx.x;
  int e;
  if (mty < 24) {
    if (mty * 128 >= meta[8]) return;
    e = meta[16 + mty];
  } else {
    e = 8;
  }
  const u16* wg = Wgt + (size_t)(e * 16 + nt) * 24 * 4096;
  const u16* wu = Wut + (size_t)(e * 16 + nt) * 24 * 4096;
  const u16* xa = Xc + (size_t)mty * 24 * 4096;

  __shared__ u16 As[2][4096], Bgs[2][4096], Bus[2][4096];

  const int tid = threadIdx.x, lane = tid & 63, wid = tid >> 6;
  const int fr = lane & 15, fq = lane >> 4;
  const int wm4 = (wid >> 1) * 4;  // row 16-block base
  const int wn4 = (wid & 1) * 4;   // col 16-block base
  const int wn = (wid & 1) * 64;
  const int ncol = nt * 128;
  const int so = wid * 1024 + lane * 8;  // gll global src offset (u16)
  const int sl = wid * 1024;             // gll LDS dst offset (u16), wave-uniform

  f32x4 accg[4][4], accu[4][4];
#pragma unroll
  for (int i = 0; i < 4; ++i)
#pragma unroll
    for (int j = 0; j < 4; ++j) {
      accg[i][j] = f32x4{0.f, 0.f, 0.f, 0.f};
      accu[i][j] = f32x4{0.f, 0.f, 0.f, 0.f};
    }

  // full chunk = 4096 u16; 4 waves x 2 gll16 x 512 u16 each
#define STAGE(c, buf)                                               \
  {                                                                 \
    gll16(xa + (size_t)(c) * 4096 + so, &As[buf][sl]);              \
    gll16(xa + (size_t)(c) * 4096 + so + 512, &As[buf][sl + 512]);  \
    gll16(wg + (size_t)(c) * 4096 + so, &Bgs[buf][sl]);             \
    gll16(wg + (size_t)(c) * 4096 + so + 512, &Bgs[buf][sl + 512]); \
    gll16(wu + (size_t)(c) * 4096 + so, &Bus[buf][sl]);             \
    gll16(wu + (size_t)(c) * 4096 + so + 512, &Bus[buf][sl + 512]); \
  }

  STAGE(0, 0)
  __syncthreads();
  int cur = 0;
  for (int c = 0; c < 24; ++c) {
    if (c < 23) STAGE(c + 1, cur ^ 1)
    s16x8 af[4], bg[4], bu[4];
#pragma unroll
    for (int i = 0; i < 4; ++i) {
      af[i] = *reinterpret_cast<const s16x8*>(&As[cur][(wm4 + i) * 512 + fq * 128 + fr * 8]);
      bg[i] = *reinterpret_cast<const s16x8*>(&Bgs[cur][(wn4 + i) * 512 + fq * 128 + fr * 8]);
      bu[i] = *reinterpret_cast<const s16x8*>(&Bus[cur][(wn4 + i) * 512 + fq * 128 + fr * 8]);
    }
#pragma unroll
    for (int j = 0; j < 4; ++j)
#pragma unroll
      for (int i = 0; i < 4; ++i) {
        accg[i][j] = __builtin_amdgcn_mfma_f32_16x16x32_bf16(af[i], bg[j], accg[i][j], 0, 0, 0);
        accu[i][j] = __builtin_amdgcn_mfma_f32_16x16x32_bf16(af[i], bu[j], accu[i][j], 0, 0, 0);
      }
    __syncthreads();
    cur ^= 1;
  }
#undef STAGE

  // epilogue: silu(g)*u -> P tiled bf16 (C/D: row=fq*4+reg, col=fr)
#pragma unroll
  for (int i = 0; i < 4; ++i)
#pragma unroll
    for (int cc = 0; cc < 4; ++cc) {
      const int rlo = fq * 4 + cc;  // row & 15 within 16-block (wm4+i)
#pragma unroll
      for (int j = 0; j < 4; ++j) {
        const int k = ncol + wn + j * 16 + fr;  // global i-col
        const float gv = accg[i][j][cc];
        const float val = (gv / (1.0f + __expf(-gv))) * accu[i][j][cc];
        P[((size_t)mty * 64 + (k >> 5)) * 4096 + (size_t)(wm4 + i) * 512 +
          ((k >> 3) & 3) * 128 + rlo * 8 + (k & 7)] = f2bf(val);
      }
    }
}

// ---------------- stage B: out += P Wd ----------------
// grid (6 nt, 40 mty); atomicAdd epilogue (out pre-zeroed; each element gets
// one shared + at most one routed contribution).
__global__ __launch_bounds__(256, 2) void stageB_kernel(
    const u16* __restrict__ P, const int* __restrict__ meta,
    const int* __restrict__ tokmap, const u16* __restrict__ Wdt,
    float* __restrict__ out) {
  const int mty = blockIdx.y, nt = blockIdx.x;
  int e;
  if (mty < 24) {
    if (mty * 128 >= meta[8]) return;
    e = meta[16 + mty];
  } else {
    e = 8;
  }
  const u16* wd = Wdt + (size_t)(e * 6 + nt) * 64 * 4096;
  const u16* pa = P + (size_t)mty * 64 * 4096;

  __shared__ u16 As[2][4096], Bs[2][4096];

  const int tid = threadIdx.x, lane = tid & 63, wid = tid >> 6;
  const int fr = lane & 15, fq = lane >> 4;
  const int wm4 = (wid >> 1) * 4;
  const int wn4 = (wid & 1) * 4;
  const int wm = (wid >> 1) * 64;
  const int wn = (wid & 1) * 64;
  const int ncol = nt * 128;
  const int so = wid * 1024 + lane * 8;
  const int sl = wid * 1024;

  f32x4 acc[4][4];
#pragma unroll
  for (int i = 0; i < 4; ++i)
#pragma unroll
    for (int j = 0; j < 4; ++j) acc[i][j] = f32x4{0.f, 0.f, 0.f, 0.f};

#define STAGEB(c, buf)                                              \
  {                                                                 \
    gll16(pa + (size_t)(c) * 4096 + so, &As[buf][sl]);              \
    gll16(pa + (size_t)(c) * 4096 + so + 512, &As[buf][sl + 512]);  \
    gll16(wd + (size_t)(c) * 4096 + so, &Bs[buf][sl]);              \
    gll16(wd + (size_t)(c) * 4096 + so + 512, &Bs[buf][sl + 512]);  \
  }

  STAGEB(0, 0)
  __syncthreads();
  int cur = 0;
  for (int c = 0; c < 64; ++c) {
    if (c < 63) STAGEB(c + 1, cur ^ 1)
    s16x8 af[4], bf[4];
#pragma unroll
    for (int i = 0; i < 4; ++i) {
      af[i] = *reinterpret_cast<const s16x8*>(&As[cur][(wm4 + i) * 512 + fq * 128 + fr * 8]);
      bf[i] = *reinterpret_cast<const s16x8*>(&Bs[cur][(wn4 + i) * 512 + fq * 128 + fr * 8]);
    }
#pragma unroll
    for (int j = 0; j < 4; ++j)
#pragma unroll
      for (int i = 0; i < 4; ++i)
        acc[i][j] = __builtin_amdgcn_mfma_f32_16x16x32_bf16(af[i], bf[j], acc[i][j], 0, 0, 0);
    __syncthreads();
    cur ^= 1;
  }
#undef STAGEB

#pragma unroll
  for (int i = 0; i < 4; ++i)
#pragma unroll
    for (int cc = 0; cc < 4; ++cc) {
      const int p = mty * 128 + wm + i * 16 + fq * 4 + cc;
      const int tok = tokmap[p];
      if (tok >= 0) {
#pragma unroll
        for (int j = 0; j < 4; ++j)
          atomicAdd(&out[(size_t)tok * HH + ncol + wn + j * 16 + fr], acc[i][j][cc]);
      }
    }
}

// ---------------- launcher ----------------
extern "C" void kernel_launch(void* const* d_in, const int* in_sizes, int n_in,
                              void* d_out, int out_size, void* d_ws, size_t ws_size,
                              hipStream_t stream) {
  (void)in_sizes; (void)n_in; (void)ws_size;
  const float* x = (const float*)d_in[0];
  const float* rw = (const float*)d_in[1];
  const float* gate_w = (const float*)d_in[2];
  const float* up_w = (const float*)d_in[3];
  const float* down_w = (const float*)d_in[4];
  const float* sh_gate = (const float*)d_in[5];
  const float* sh_up = (const float*)d_in[6];
  const float* sh_down = (const float*)d_in[7];
  float* out = (float*)d_out;

  char* ws = (char*)d_ws;
  size_t off = 0;
  u16* Xc = (u16*)(ws + off);  off += (size_t)(RSLOTS + TT) * HH * sizeof(u16);   // 7.9MB
  u16* P = (u16*)(ws + off);   off += (size_t)(RSLOTS + TT) * II * sizeof(u16);   // 21MB
  u16* Wgt = (u16*)(ws + off); off += (size_t)9 * 16 * 24 * 4096 * sizeof(u16);   // 28.3MB
  u16* Wut = (u16*)(ws + off); off += (size_t)9 * 16 * 24 * 4096 * sizeof(u16);   // 28.3MB
  u16* Wdt = (u16*)(ws + off); off += (size_t)9 * 6 * 64 * 4096 * sizeof(u16);    // 28.3MB
  float* score = (float*)(ws + off);   off += TT * sizeof(float);
  int* list = (int*)(ws + off);        off += (size_t)NE * TT * sizeof(int);
  int* cnt = (int*)(ws + off);         off += 16 * sizeof(int);
  float* probsum = (float*)(ws + off); off += 16 * sizeof(float);
  int* meta = (int*)(ws + off);        off += 64 * sizeof(int);
  int* tokmap = (int*)(ws + off);

  hipMemsetAsync(d_out, 0, (size_t)out_size * sizeof(float), stream);
  hipMemsetAsync(cnt, 0, 16 * sizeof(int) + 16 * sizeof(float), stream);
  wconv_kernel<<<dim3(2592), dim3(256), 0, stream>>>(gate_w, up_w, down_w, sh_gate,
                                                     sh_up, sh_down, Wgt, Wut, Wdt);
  router_kernel<<<dim3(512), dim3(256), 0, stream>>>(x, rw, score, list, cnt, probsum);
  plan_kernel<<<dim3(1), dim3(64), 0, stream>>>(cnt, probsum, meta, out);
  gather_kernel<<<dim3(1920), dim3(256), 0, stream>>>(x, score, list, cnt, meta, Xc,
                                                      tokmap);
  stageA_kernel<<<dim3(16, 40, 1), dim3(256), 0, stream>>>(Xc, meta, Wgt, Wut, P);
  stageB_kernel<<<dim3(6, 40, 1), dim3(256), 0, stream>>>(P, meta, tokmap, Wdt, out);
}